// Round 1
// baseline (646.831 us; speedup 1.0000x reference)
//
#include <hip/hip_runtime.h>
#include <math.h>

#define T_DIM 2048
#define N_DIM 64
#define D_DIM 1024
#define TC    16                    // t's per wave-chunk
#define CHUNKS (T_DIM / TC)         // 128 chunks over T
#define EPS 1e-6f
#define HALF_LOG_2PI 0.91893853320467274178f

__global__ void zero_out_kernel(float* out) {
    out[threadIdx.x] = 0.0f;
}

// One wave handles (sequence n, t-chunk of 16 rows).
// Lanes 0-31 own even rows of the chunk, lanes 32-63 own odd rows.
// Streaming phase: pure load+FMA, explicit A/B double-buffer so 8 dwordx4
// loads are always in flight (no shuffle/waitcnt stalls in the stream).
// Reduction phase: 16 independent 5-step butterfly chains afterwards.
// Validity (t < len) is masked only at accumulation; reading the full
// 16-row chunk costs +0.7% BW and buys a compile-time-unrollable loop.
__global__ __launch_bounds__(256, 2) void gnll_kernel(
    const float* __restrict__ y,    // (T, N)
    const float* __restrict__ x,    // (T, N, D)
    const float* __restrict__ W,    // (2, D)
    const int*   __restrict__ lens, // (N)
    float*       __restrict__ out)  // (N)
{
    const int lane = threadIdx.x & 63;
    const int wave = threadIdx.x >> 6;
    const int wg   = blockIdx.x * 4 + wave;     // global wave id
    const int n     = wg & (N_DIM - 1);         // consecutive waves -> consecutive n
    const int chunk = wg >> 6;                  // which t-chunk
    const int len = lens[n];
    const int t0 = chunk * TC;
    if (t0 >= len) return;                      // skip fully-masked chunks

    const int half = lane >> 5;                 // 0: even rows, 1: odd rows
    const int c    = lane & 31;                 // float4 slot within the row

    // W fragments resident in registers (64 VGPRs), hot in L1 across waves.
    const float4* W0 = (const float4*)W;
    const float4* W1 = (const float4*)(W + D_DIM);
    float4 w0[8], w1[8];
#pragma unroll
    for (int j = 0; j < 8; ++j) {
        w0[j] = W0[j * 32 + c];
        w1[j] = W1[j * 32 + c];
    }

    // Base for this lane's first row (t0+half); +2 rows per pair step.
    const float4* xp = (const float4*)(x + ((size_t)(t0 + half) * N_DIM + n) * D_DIM) + c;
    const size_t PSTR = (size_t)2 * N_DIM * (D_DIM / 4);  // float4 units per 2 rows

#define LOAD8(buf, ptr) do {                                                   \
        _Pragma("unroll")                                                      \
        for (int j = 0; j < 8; ++j) buf[j] = (ptr)[j * 32];                    \
    } while (0)

#define DOT8(buf, mm, ss) do {                                                 \
        mm = 0.0f; ss = 0.0f;                                                  \
        _Pragma("unroll")                                                      \
        for (int j = 0; j < 8; ++j) {                                          \
            mm += buf[j].x * w0[j].x + buf[j].y * w0[j].y                      \
                + buf[j].z * w0[j].z + buf[j].w * w0[j].w;                     \
            ss += buf[j].x * w1[j].x + buf[j].y * w1[j].y                      \
                + buf[j].z * w1[j].z + buf[j].w * w1[j].w;                     \
        }                                                                      \
    } while (0)

    float4 xA[8], xB[8];
    float m[8], s[8];
    float yv[8];

    LOAD8(xA, xp);                              // prime pair 0
    // y loads (uniform per half-wave, 8 total) issued early, hidden by stream
#pragma unroll
    for (int p = 0; p < 8; ++p)
        yv[p] = y[(size_t)(t0 + 2 * p + half) * N_DIM + n];

    // 8 pairs, fully unrolled, 2-deep pipelined: prefetch p+1 while dotting p.
#pragma unroll
    for (int p = 0; p < 8; ++p) {
        const float4* nxt = xp + (size_t)(p + 1) * PSTR;
        if ((p & 1) == 0) {
            if (p < 7) LOAD8(xB, nxt);
            DOT8(xA, m[p], s[p]);
        } else {
            if (p < 7) LOAD8(xA, nxt);
            DOT8(xB, m[p], s[p]);
        }
    }

    // 16 independent butterfly reduce chains (within each 32-lane half).
#pragma unroll
    for (int off = 16; off > 0; off >>= 1) {
#pragma unroll
        for (int p = 0; p < 8; ++p) {
            m[p] += __shfl_xor(m[p], off, 64);
            s[p] += __shfl_xor(s[p], off, 64);
        }
    }

    // nll for this half's 8 rows; predicated accumulate (no divergence).
    float acc = 0.0f;
#pragma unroll
    for (int p = 0; p < 8; ++p) {
        const int t = t0 + 2 * p + half;
        const float sg   = 1.0f / (1.0f + __expf(-s[p]));
        const float var  = fmaxf(sg, EPS);
        const float diff = yv[p] - m[p];
        const float nll  = 0.5f * (__logf(var) + diff * diff / var) + HALF_LOG_2PI;
        acc += ((t < len) & (c == 0)) ? nll : 0.0f;
    }
    acc += __shfl_xor(acc, 32, 64);             // combine the two halves
    if (lane == 0) atomicAdd(out + n, acc);

#undef LOAD8
#undef DOT8
}

extern "C" void kernel_launch(void* const* d_in, const int* in_sizes, int n_in,
                              void* d_out, int out_size, void* d_ws, size_t ws_size,
                              hipStream_t stream) {
    const float* y    = (const float*)d_in[0];
    const float* x    = (const float*)d_in[1];
    const float* W    = (const float*)d_in[2];
    const int*   lens = (const int*)d_in[3];
    float* out = (float*)d_out;

    zero_out_kernel<<<1, N_DIM, 0, stream>>>(out);
    // N_DIM * CHUNKS waves / 4 waves-per-block = 2048 blocks
    gnll_kernel<<<(N_DIM * CHUNKS) / 4, 256, 0, stream>>>(y, x, W, lens, out);
}

// Round 2
// 641.811 us; speedup vs baseline: 1.0078x; 1.0078x over previous
//
#include <hip/hip_runtime.h>
#include <math.h>

#define T_DIM 2048
#define N_DIM 64
#define D_DIM 1024
#define TB    16                     // t's per wave-chunk
#define TBLKS (T_DIM / TB)           // 128 t-blocks
#define NPAIRS (N_DIM / 2)           // 32 n-pairs
#define EPS 1e-6f
#define HALF_LOG_2PI 0.91893853320467274178f

__global__ void zero_out_kernel(float* out) {
    out[threadIdx.x] = 0.0f;
}

// Contiguity-first decomposition. lens is sorted DESCENDING (PackedSequence),
// so valid rows at each t are a contiguous n-prefix. A wave owns an n-PAIR
// (lanes 0-31 -> row n, lanes 32-63 -> row n+1) and walks 16 consecutive t's:
// each t-step reads 8 KB CONTIGUOUS (rows (t,n),(t,n+1) adjacent), and the
// 4 waves of a block cover n..n+7 at the same t = 32 KB contiguous runs.
// Previous kernels strode 256 KB between consecutive 4 KB rows; this is the
// last untested bandwidth mechanism (occupancy/pipelining/reduction placement
// all proven neutral in rounds 0-1).
__global__ __launch_bounds__(256) void gnll_kernel(
    const float* __restrict__ y,    // (T, N)
    const float* __restrict__ x,    // (T, N, D)
    const float* __restrict__ W,    // (2, D)
    const int*   __restrict__ lens, // (N)
    float*       __restrict__ out)  // (N)
{
    const int lane = threadIdx.x & 63;
    const int wave = threadIdx.x >> 6;
    const int wg   = blockIdx.x * 4 + wave;     // global wave id
    const int pair = wg & (NPAIRS - 1);         // consecutive waves -> consecutive n-pairs
    const int tblk = wg >> 5;                   // which 16-t block
    const int half = lane >> 5;                 // 0: row n=2*pair, 1: row n=2*pair+1
    const int c    = lane & 31;                 // float4 slot within the row
    const int n    = 2 * pair + half;

    const int t0     = tblk * TB;
    const int len_hi = lens[2 * pair];          // pair's larger len (sorted desc)
    if (t0 >= len_hi) return;                   // whole pair masked at these t's
    const int t1    = min(t0 + TB, len_hi);
    const int len_n = lens[n];                  // own row's len (odd row may be shorter)

    // W fragments resident in registers, shared by both halves (same c layout).
    const float4* W0 = (const float4*)W;
    const float4* W1 = (const float4*)(W + D_DIM);
    float4 w0[8], w1[8];
#pragma unroll
    for (int j = 0; j < 8; ++j) {
        w0[j] = W0[j * 32 + c];
        w1[j] = W1[j * 32 + c];
    }

    const size_t TSTR = (size_t)N_DIM * (D_DIM / 4);   // float4 per t-step
    const float4* xp = (const float4*)(x + ((size_t)t0 * N_DIM + n) * D_DIM) + c;

    float acc = 0.0f;

#define BODY(T_IDX, PTR) do {                                                  \
        float m = 0.0f, s = 0.0f;                                              \
        _Pragma("unroll")                                                      \
        for (int j = 0; j < 8; ++j) {                                          \
            const float4 xv = (PTR)[j * 32];                                   \
            m += xv.x * w0[j].x + xv.y * w0[j].y                               \
               + xv.z * w0[j].z + xv.w * w0[j].w;                              \
            s += xv.x * w1[j].x + xv.y * w1[j].y                               \
               + xv.z * w1[j].z + xv.w * w1[j].w;                              \
        }                                                                      \
        _Pragma("unroll")                                                      \
        for (int off = 16; off > 0; off >>= 1) {                               \
            m += __shfl_xor(m, off, 64);                                       \
            s += __shfl_xor(s, off, 64);                                       \
        }                                                                      \
        const float yv   = y[(size_t)(T_IDX) * N_DIM + n];                     \
        const float sg   = 1.0f / (1.0f + __expf(-s));                         \
        const float var  = fmaxf(sg, EPS);                                     \
        const float diff = yv - m;                                             \
        const float nll  = 0.5f * (__logf(var) + diff * diff / var)            \
                         + HALF_LOG_2PI;                                       \
        acc += (((T_IDX) < len_n) & (c == 0)) ? nll : 0.0f;                    \
    } while (0)

    if (t1 - t0 == TB) {
        // Full chunk: compile-time trip count -> deep pipelining across 16
        // independent t-iterations (16 independent load/reduce chains).
#pragma unroll
        for (int i = 0; i < TB; ++i) {
            BODY(t0 + i, xp + (size_t)i * TSTR);
        }
    } else {
        // Boundary chunk (once per pair): dynamic trip count.
        for (int t = t0; t < t1; ++t, xp += TSTR) {
            BODY(t, xp);
        }
    }
#undef BODY

    // Lane c==0 of each half holds its row's partial sum.
    if (c == 0) atomicAdd(out + n, acc);
}

extern "C" void kernel_launch(void* const* d_in, const int* in_sizes, int n_in,
                              void* d_out, int out_size, void* d_ws, size_t ws_size,
                              hipStream_t stream) {
    const float* y    = (const float*)d_in[0];
    const float* x    = (const float*)d_in[1];
    const float* W    = (const float*)d_in[2];
    const int*   lens = (const int*)d_in[3];
    float* out = (float*)d_out;

    zero_out_kernel<<<1, N_DIM, 0, stream>>>(out);
    // NPAIRS * TBLKS waves / 4 waves-per-block = 1024 blocks
    gnll_kernel<<<(NPAIRS * TBLKS) / 4, 256, 0, stream>>>(y, x, W, lens, out);
}